// Round 1
// baseline (242.427 us; speedup 1.0000x reference)
//
#include <hip/hip_runtime.h>
#include <hip/hip_bf16.h>

// PositionalEncoding: out[b,s,d] = x[b,s,d] + pe[s,d]
//   pe[s,d] = sin(s / 10000^((d/2)/S)) if d even else cos(...)
// x: [B=8, S=4096, D=1024] float32. Memory-bound: 268 MB traffic -> ~43 us ideal.

#define PE_B 8
#define PE_S 4096
#define PE_D 1024

__global__ __launch_bounds__(256) void PositionalEncoding_84095459656362_kernel(
    const float* __restrict__ x, float* __restrict__ out) {
    // One thread per (s, 4 consecutive d). t in [0, S*D/4).
    const int t  = blockIdx.x * blockDim.x + threadIdx.x;
    const int d4 = (t & (PE_D / 4 - 1)) << 2;  // d base: 0,4,...,1020
    const int s  = t >> 8;                     // t / (D/4)

    // angle = s * 10000^(-k/S) = s * exp2(k * (-log2(10000)/S))
    const float c  = -0.0032440703857f;        // -log2(10000)/4096
    const float k0 = (float)(d4 >> 1);
    const float a0 = (float)s * __builtin_exp2f(k0 * c);
    const float a1 = (float)s * __builtin_exp2f((k0 + 1.0f) * c);

    float4 pe;
    __sincosf(a0, &pe.x, &pe.y);   // d even -> sin, d odd -> cos
    __sincosf(a1, &pe.z, &pe.w);

    size_t off = (size_t)s * PE_D + d4;
    const size_t batch_stride = (size_t)PE_S * PE_D;
#pragma unroll
    for (int b = 0; b < PE_B; ++b) {
        const float4 v = *(const float4*)(x + off);
        float4 r;
        r.x = v.x + pe.x;
        r.y = v.y + pe.y;
        r.z = v.z + pe.z;
        r.w = v.w + pe.w;
        *(float4*)(out + off) = r;
        off += batch_stride;
    }
}

extern "C" void kernel_launch(void* const* d_in, const int* in_sizes, int n_in,
                              void* d_out, int out_size, void* d_ws, size_t ws_size,
                              hipStream_t stream) {
    const float* x = (const float*)d_in[0];
    float* out = (float*)d_out;
    const int threads = PE_S * PE_D / 4;           // 1,048,576
    PositionalEncoding_84095459656362_kernel<<<threads / 256, 256, 0, stream>>>(x, out);
}

// Round 3
// 221.894 us; speedup vs baseline: 1.0925x; 1.0925x over previous
//
#include <hip/hip_runtime.h>
#include <hip/hip_bf16.h>

// PositionalEncoding: out[b,s,d] = x[b,s,d] + pe[s,d]
//   pe[s,d] = sin(s / 10000^((d/2)/S)) if d even else cos(...)
// x: [B=8, S=4096, D=1024] float32.
//
// R1 lesson: 8-batch loop per thread serialized memory ops (24 VGPRs -> 1
// load in flight) -> 2.28 TB/s. This version: flat 1-float4-per-thread copy
// pattern (m13-style, 6.29 TB/s proven), MLP from wave count not ILP.
// R2 lesson: __builtin_nontemporal_store needs a clang ext_vector_type,
// not HIP_vector_type float4.

#define PE_S 4096
#define PE_D 1024
#define N4   (8 * PE_S * PE_D / 4)   // 8,388,608 float4 elements

typedef float f32x4 __attribute__((ext_vector_type(4)));

__global__ __launch_bounds__(256) void PositionalEncoding_84095459656362_kernel(
    const float* __restrict__ x, float* __restrict__ out) {
    const int i  = blockIdx.x * blockDim.x + threadIdx.x;   // float4 index
    const int d4 = (i & (PE_D / 4 - 1)) << 2;               // d base: 0..1020
    const int s  = (i >> 8) & (PE_S - 1);                   // sequence pos

    // angle(k) = s * 10000^(-k/S) = s * exp2(k * c), c = -log2(10000)/4096
    const float c   = -0.0032440703857f;
    const float r1  = 0.99775390625f;                        // 10000^(-1/4096)
    const float e0  = __builtin_exp2f((float)(d4 >> 1) * c);
    const float a0  = (float)s * e0;
    const float a1  = a0 * r1;

    float s0, c0, s1, c1;
    __sincosf(a0, &s0, &c0);   // d even -> sin, d odd -> cos
    __sincosf(a1, &s1, &c1);

    const f32x4 v = ((const f32x4*)x)[i];
    f32x4 r;
    r.x = v.x + s0;
    r.y = v.y + c0;
    r.z = v.z + s1;
    r.w = v.w + c1;
    __builtin_nontemporal_store(r, &((f32x4*)out)[i]);
}

extern "C" void kernel_launch(void* const* d_in, const int* in_sizes, int n_in,
                              void* d_out, int out_size, void* d_ws, size_t ws_size,
                              hipStream_t stream) {
    const float* x = (const float*)d_in[0];
    float* out = (float*)d_out;
    PositionalEncoding_84095459656362_kernel<<<N4 / 256, 256, 0, stream>>>(x, out);
}